// Round 1
// baseline (314.609 us; speedup 1.0000x reference)
//
#include <hip/hip_runtime.h>

// AttnBlock on MI355X — round 1: correctness-first bf16-MFMA pipeline.
// B=2, C=512, N=4096 (16^3). All GEMMs via mfma_f32_16x16x32_bf16.

typedef __bf16 bf16;
typedef __attribute__((ext_vector_type(8))) __bf16 bf16x8;
typedef __attribute__((ext_vector_type(4))) __bf16 bf16x4;
typedef __attribute__((ext_vector_type(4))) float f32x4;

#define CC 512
#define NN 4096
#define GSIZE 16   // channels per group (512/32)

#define BM 128
#define BN 128
#define BK 64
#define LDT 72     // padded LDS row stride (144B = 9*16B: aligned b128, 2-way banks)

// ---------------------------------------------------------------------------
// Generic 128x128 MFMA GEMM accumulator. A: row-major [M,K] (lda).
// BMODE 0: B global row-major [K,N] (ldb) -> transpose-stage into BT_lds[n][k]
// BMODE 1: B global row-major [N,K] (ldb) -> direct stage (already BT)
// 256 threads = 4 waves (2x2), each wave 64x64 = 4x4 fragments of 16x16.
// Fragment layout assumption (risk): A[m][k]: m=lane&15, k=(lane>>4)*8+i;
// B[k][n]: n=lane&15, k=(lane>>4)*8+i; D: col=lane&15, row=(lane>>4)*4+reg.
// ---------------------------------------------------------------------------
template<int BMODE>
__device__ inline void gemm_accum(const bf16* __restrict__ A, int lda,
                                  const bf16* __restrict__ B, int ldb,
                                  int K, int m0, int n0, f32x4 acc[4][4])
{
    __shared__ __align__(16) bf16 Als[BM][LDT];
    __shared__ __align__(16) bf16 Bls[BN][LDT];
    const int t    = threadIdx.x;
    const int lane = t & 63;
    const int wid  = t >> 6;
    const int wm   = (wid >> 1) * 64;
    const int wn   = (wid & 1) * 64;
    const int fr   = lane & 15;
    const int kg   = (lane >> 4) * 8;

    for (int k0 = 0; k0 < K; k0 += BK) {
        // --- stage A: 128x64 bf16, fully vectorized/coalesced ---
        #pragma unroll
        for (int i = 0; i < 4; ++i) {
            int e = (i * 256 + t) * 8;
            int r = e >> 6, c = e & 63;
            *(bf16x8*)&Als[r][c] =
                *(const bf16x8*)(A + (size_t)(m0 + r) * lda + (k0 + c));
        }
        // --- stage B into BT layout [n][k] ---
        if (BMODE == 1) {
            #pragma unroll
            for (int i = 0; i < 4; ++i) {
                int e = (i * 256 + t) * 8;
                int r = e >> 6, c = e & 63;
                *(bf16x8*)&Bls[r][c] =
                    *(const bf16x8*)(B + (size_t)(n0 + r) * ldb + (k0 + c));
            }
        } else {
            #pragma unroll
            for (int i = 0; i < 4; ++i) {
                int idx = i * 256 + t;
                int n   = idx & 127;
                int kk0 = (idx >> 7) * 8;
                bf16x8 v;
                #pragma unroll
                for (int j = 0; j < 8; ++j)
                    v[j] = B[(size_t)(k0 + kk0 + j) * ldb + (n0 + n)];
                *(bf16x8*)&Bls[n][kk0] = v;
            }
        }
        __syncthreads();
        // --- compute: 2 k-halves x 16 MFMAs per wave ---
        #pragma unroll
        for (int kk = 0; kk < BK; kk += 32) {
            bf16x8 af[4], bg[4];
            #pragma unroll
            for (int f = 0; f < 4; ++f) {
                af[f] = *(const bf16x8*)&Als[wm + f * 16 + fr][kk + kg];
                bg[f] = *(const bf16x8*)&Bls[wn + f * 16 + fr][kk + kg];
            }
            #pragma unroll
            for (int fm = 0; fm < 4; ++fm)
                #pragma unroll
                for (int fn = 0; fn < 4; ++fn)
                    acc[fm][fn] = __builtin_amdgcn_mfma_f32_16x16x32_bf16(
                        af[fm], bg[fn], acc[fm][fn], 0, 0, 0);
        }
        __syncthreads();
    }
}

// ---------------------------------------------------------------------------
// Small prep kernels
// ---------------------------------------------------------------------------
__global__ __launch_bounds__(256) void convert_w_kernel(
    const float* __restrict__ qw, const float* __restrict__ kw,
    const float* __restrict__ vw, const float* __restrict__ pw,
    bf16* __restrict__ dst)
{
    const int which = blockIdx.y;
    const float* src = which == 0 ? qw : which == 1 ? kw : which == 2 ? vw : pw;
    bf16* d = dst + (size_t)which * (CC * CC);
    const int f4 = blockIdx.x * 256 + threadIdx.x;   // 0..65535
    float4 v = ((const float4*)src)[f4];
    bf16x4 o;
    o[0] = (bf16)v.x; o[1] = (bf16)v.y; o[2] = (bf16)v.z; o[3] = (bf16)v.w;
    ((bf16x4*)d)[f4] = o;
}

__global__ __launch_bounds__(256) void gn_stats_kernel(
    const float* __restrict__ x, float* __restrict__ mr)
{
    const int bg = blockIdx.x;                       // 0..63 = b*32+g
    const float4* base = (const float4*)(x + (size_t)bg * GSIZE * NN);
    const int t = threadIdx.x;
    float s = 0.f, sq = 0.f;
    #pragma unroll 4
    for (int i = 0; i < 64; ++i) {
        float4 v = base[i * 256 + t];
        s  += v.x + v.y + v.z + v.w;
        sq += v.x * v.x + v.y * v.y + v.z * v.z + v.w * v.w;
    }
    #pragma unroll
    for (int o = 32; o > 0; o >>= 1) { s += __shfl_xor(s, o); sq += __shfl_xor(sq, o); }
    __shared__ float rs[4], rq[4];
    const int lane = t & 63, wid = t >> 6;
    if (lane == 0) { rs[wid] = s; rq[wid] = sq; }
    __syncthreads();
    if (t == 0) {
        float S = rs[0] + rs[1] + rs[2] + rs[3];
        float Q = rq[0] + rq[1] + rq[2] + rq[3];
        const float invn = 1.f / 65536.f;
        float mean = S * invn;
        float var  = Q * invn - mean * mean;
        mr[bg * 2]     = mean;
        mr[bg * 2 + 1] = rsqrtf(var + 1e-6f);
    }
}

__global__ __launch_bounds__(256) void gn_apply_kernel(
    const float* __restrict__ x, const float* __restrict__ gw,
    const float* __restrict__ gb, const float* __restrict__ mr,
    bf16* __restrict__ h)
{
    const size_t f4 = (size_t)blockIdx.x * 256 + threadIdx.x;
    const size_t e  = f4 * 4;
    const int c  = (int)((e >> 12) & 511);           // (e/4096)%512
    const int bg = (int)(e >> 16);                   // e/65536 = b*32+g
    const float mean = mr[bg * 2], rstd = mr[bg * 2 + 1];
    const float w  = gw[c] * rstd;
    const float bb = gb[c] - mean * w;
    float4 v = ((const float4*)x)[f4];
    bf16x4 o;
    o[0] = (bf16)(v.x * w + bb);
    o[1] = (bf16)(v.y * w + bb);
    o[2] = (bf16)(v.z * w + bb);
    o[3] = (bf16)(v.w * w + bb);
    ((bf16x4*)h)[f4] = o;
}

// ---------------------------------------------------------------------------
// GEMM wrapper kernels
// ---------------------------------------------------------------------------
__global__ __launch_bounds__(256) void qkv_gemm_kernel(
    const bf16* __restrict__ wq, const bf16* __restrict__ wk, const bf16* __restrict__ wv,
    const bf16* __restrict__ h,
    const float* __restrict__ qb, const float* __restrict__ kb, const float* __restrict__ vb,
    bf16* __restrict__ qT, bf16* __restrict__ ko, bf16* __restrict__ vo)
{
    const int z = blockIdx.z, b = z / 3, w = z % 3;
    const bf16* A = (w == 0) ? wq : (w == 1) ? wk : wv;
    const float* bias = (w == 0) ? qb : (w == 1) ? kb : vb;
    const bf16* B = h + (size_t)b * CC * NN;
    const int m0 = blockIdx.y * BM, n0 = blockIdx.x * BN;
    f32x4 acc[4][4] = {};
    gemm_accum<0>(A, CC, B, NN, CC, m0, n0, acc);

    const int t = threadIdx.x, lane = t & 63, wid = t >> 6;
    const int wm = (wid >> 1) * 64, wn = (wid & 1) * 64;
    const int cf = lane & 15, rb = (lane >> 4) * 4;
    #pragma unroll
    for (int fm = 0; fm < 4; ++fm)
      #pragma unroll
      for (int fn = 0; fn < 4; ++fn)
        #pragma unroll
        for (int r = 0; r < 4; ++r) {
            int row = m0 + wm + fm * 16 + rb + r;
            int col = n0 + wn + fn * 16 + cf;
            float vv = acc[fm][fn][r] + bias[row];
            if (w == 0) {
                // q stored transposed: qT[b][n][c] so S-GEMM's A is row-major
                qT[((size_t)b * NN + col) * CC + row] = (bf16)vv;
            } else {
                bf16* o = ((w == 1) ? ko : vo) + (size_t)b * CC * NN;
                o[(size_t)row * NN + col] = (bf16)vv;
            }
        }
}

__global__ __launch_bounds__(256) void s_gemm_kernel(
    const bf16* __restrict__ qT_b, const bf16* __restrict__ k_b,
    float* __restrict__ S)
{
    const int m0 = blockIdx.y * BM, n0 = blockIdx.x * BN;
    f32x4 acc[4][4] = {};
    gemm_accum<0>(qT_b, CC, k_b, NN, CC, m0, n0, acc);
    const int t = threadIdx.x, lane = t & 63, wid = t >> 6;
    const int wm = (wid >> 1) * 64, wn = (wid & 1) * 64;
    const int cf = lane & 15, rb = (lane >> 4) * 4;
    #pragma unroll
    for (int fm = 0; fm < 4; ++fm)
      #pragma unroll
      for (int fn = 0; fn < 4; ++fn)
        #pragma unroll
        for (int r = 0; r < 4; ++r)
            S[(size_t)(m0 + wm + fm * 16 + rb + r) * NN
              + (n0 + wn + fn * 16 + cf)] = acc[fm][fn][r];
}

__global__ __launch_bounds__(256) void softmax_kernel(
    const float* __restrict__ S, bf16* __restrict__ P)
{
    const int i = blockIdx.x, t = threadIdx.x;
    const float scale = 0.044194173824159216f;       // 512^-0.5
    const float4* row = (const float4*)(S + (size_t)i * NN);
    float v[16], e[16];
    float m = -3.4e38f;
    #pragma unroll
    for (int w = 0; w < 4; ++w) {
        float4 q = row[t + 256 * w];
        v[w * 4 + 0] = q.x; v[w * 4 + 1] = q.y; v[w * 4 + 2] = q.z; v[w * 4 + 3] = q.w;
        m = fmaxf(m, fmaxf(fmaxf(q.x, q.y), fmaxf(q.z, q.w)));
    }
    #pragma unroll
    for (int o = 32; o > 0; o >>= 1) m = fmaxf(m, __shfl_xor(m, o));
    __shared__ float rmax[4], rsum[4];
    const int lane = t & 63, wid = t >> 6;
    if (lane == 0) rmax[wid] = m;
    __syncthreads();
    m = fmaxf(fmaxf(rmax[0], rmax[1]), fmaxf(rmax[2], rmax[3]));
    const float mm = m * scale;
    float s = 0.f;
    #pragma unroll
    for (int j = 0; j < 16; ++j) { e[j] = __expf(v[j] * scale - mm); s += e[j]; }
    #pragma unroll
    for (int o = 32; o > 0; o >>= 1) s += __shfl_xor(s, o);
    if (lane == 0) rsum[wid] = s;
    __syncthreads();
    s = rsum[0] + rsum[1] + rsum[2] + rsum[3];
    const float inv = 1.f / s;
    bf16x4* out = (bf16x4*)(P + (size_t)i * NN);
    #pragma unroll
    for (int w = 0; w < 4; ++w) {
        bf16x4 o4;
        o4[0] = (bf16)(e[w * 4 + 0] * inv);
        o4[1] = (bf16)(e[w * 4 + 1] * inv);
        o4[2] = (bf16)(e[w * 4 + 2] * inv);
        o4[3] = (bf16)(e[w * 4 + 3] * inv);
        out[t + 256 * w] = o4;
    }
}

__global__ __launch_bounds__(256) void pv_gemm_kernel(
    const bf16* __restrict__ v_b, const bf16* __restrict__ P,
    bf16* __restrict__ attn_b, int i0)
{
    const int m0 = blockIdx.y * BM, n0 = blockIdx.x * BN;
    f32x4 acc[4][4] = {};
    gemm_accum<1>(v_b, NN, P, NN, NN, m0, n0, acc);   // B = P [i][j]: NK layout
    const int t = threadIdx.x, lane = t & 63, wid = t >> 6;
    const int wm = (wid >> 1) * 64, wn = (wid & 1) * 64;
    const int cf = lane & 15, rb = (lane >> 4) * 4;
    #pragma unroll
    for (int fm = 0; fm < 4; ++fm)
      #pragma unroll
      for (int fn = 0; fn < 4; ++fn)
        #pragma unroll
        for (int r = 0; r < 4; ++r) {
            int row = m0 + wm + fm * 16 + rb + r;     // c
            int col = n0 + wn + fn * 16 + cf;         // i within chunk
            attn_b[(size_t)row * NN + (i0 + col)] = (bf16)acc[fm][fn][r];
        }
}

__global__ __launch_bounds__(256) void proj_gemm_kernel(
    const bf16* __restrict__ wp, const bf16* __restrict__ attn,
    const float* __restrict__ pb, const float* __restrict__ x,
    float* __restrict__ out)
{
    const int b = blockIdx.z;
    const int m0 = blockIdx.y * BM, n0 = blockIdx.x * BN;
    f32x4 acc[4][4] = {};
    gemm_accum<0>(wp, CC, attn + (size_t)b * CC * NN, NN, CC, m0, n0, acc);
    const int t = threadIdx.x, lane = t & 63, wid = t >> 6;
    const int wm = (wid >> 1) * 64, wn = (wid & 1) * 64;
    const int cf = lane & 15, rb = (lane >> 4) * 4;
    #pragma unroll
    for (int fm = 0; fm < 4; ++fm)
      #pragma unroll
      for (int fn = 0; fn < 4; ++fn)
        #pragma unroll
        for (int r = 0; r < 4; ++r) {
            int row = m0 + wm + fm * 16 + rb + r;
            int col = n0 + wn + fn * 16 + cf;
            size_t idx = (size_t)b * CC * NN + (size_t)row * NN + col;
            out[idx] = acc[fm][fn][r] + pb[row] + x[idx];
        }
}

// ---------------------------------------------------------------------------
extern "C" void kernel_launch(void* const* d_in, const int* in_sizes, int n_in,
                              void* d_out, int out_size, void* d_ws, size_t ws_size,
                              hipStream_t stream)
{
    const float* x   = (const float*)d_in[0];
    const float* gnw = (const float*)d_in[1];
    const float* gnb = (const float*)d_in[2];
    const float* qw  = (const float*)d_in[3];
    const float* qb  = (const float*)d_in[4];
    const float* kw  = (const float*)d_in[5];
    const float* kb  = (const float*)d_in[6];
    const float* vw  = (const float*)d_in[7];
    const float* vb  = (const float*)d_in[8];
    const float* pw  = (const float*)d_in[9];
    const float* pb  = (const float*)d_in[10];
    float* out = (float*)d_out;

    char* ws = (char*)d_ws;
    size_t off = 0;
    auto alloc = [&](size_t bytes) -> char* {
        char* p = ws + off;
        off = (off + bytes + 255) & ~(size_t)255;
        return p;
    };
    const size_t CN = (size_t)CC * NN;
    bf16*  wbf  = (bf16*)alloc(4 * (size_t)CC * CC * sizeof(bf16));
    bf16*  hb   = (bf16*)alloc(2 * CN * sizeof(bf16));
    bf16*  qT   = (bf16*)alloc(2 * CN * sizeof(bf16));
    bf16*  kbm  = (bf16*)alloc(2 * CN * sizeof(bf16));
    bf16*  vbm  = (bf16*)alloc(2 * CN * sizeof(bf16));
    bf16*  attn = (bf16*)alloc(2 * CN * sizeof(bf16));
    float* mr   = (float*)alloc(64 * 2 * sizeof(float));

    // Pick the largest i-chunk whose S(fp32)+P(bf16) scratch fits ws_size.
    int CHUNK = NN;
    while (CHUNK > 256 && off + (size_t)CHUNK * NN * 6 + 1024 > ws_size) CHUNK >>= 1;
    float* S = (float*)alloc((size_t)CHUNK * NN * sizeof(float));
    bf16*  P = (bf16*)alloc((size_t)CHUNK * NN * sizeof(bf16));

    convert_w_kernel<<<dim3(256, 4), 256, 0, stream>>>(qw, kw, vw, pw, wbf);
    gn_stats_kernel<<<64, 256, 0, stream>>>(x, mr);
    gn_apply_kernel<<<4096, 256, 0, stream>>>(x, gnw, gnb, mr, hb);

    qkv_gemm_kernel<<<dim3(NN / BN, CC / BM, 6), 256, 0, stream>>>(
        wbf, wbf + (size_t)CC * CC, wbf + 2 * (size_t)CC * CC, hb,
        qb, kb, vb, qT, kbm, vbm);

    for (int b = 0; b < 2; ++b) {
        const bf16* qT_b = qT  + (size_t)b * CN;
        const bf16* k_b  = kbm + (size_t)b * CN;
        const bf16* v_b  = vbm + (size_t)b * CN;
        bf16* attn_b     = attn + (size_t)b * CN;
        for (int i0 = 0; i0 < NN; i0 += CHUNK) {
            s_gemm_kernel<<<dim3(NN / BN, CHUNK / BM), 256, 0, stream>>>(
                qT_b + (size_t)i0 * CC, k_b, S);
            softmax_kernel<<<CHUNK, 256, 0, stream>>>(S, P);
            pv_gemm_kernel<<<dim3(CHUNK / BN, CC / BM), 256, 0, stream>>>(
                v_b, P, attn_b, i0);
        }
    }

    proj_gemm_kernel<<<dim3(NN / BN, CC / BM, 2), 256, 0, stream>>>(
        wbf + 3 * (size_t)CC * CC, attn, pb, x, out);
}

// Round 2
// 256.885 us; speedup vs baseline: 1.2247x; 1.2247x over previous
//
#include <hip/hip_runtime.h>

// AttnBlock on MI355X — round 2: all-vectorized staging via global_load_lds +
// XOR swizzle, exp fused into S-GEMM (no softmax pass), split-K PV.

typedef __bf16 bf16;
typedef __attribute__((ext_vector_type(8))) __bf16 bf16x8;
typedef __attribute__((ext_vector_type(4))) __bf16 bf16x4;
typedef __attribute__((ext_vector_type(4))) float f32x4;

#define CC 512
#define NN 4096
#define BM 128
#define BN 128
#define BK 64
#define SCALE 0.044194173824159216f   // 512^-0.5

__device__ __forceinline__ void gload16(const bf16* g, bf16* l) {
    __builtin_amdgcn_global_load_lds(
        (const __attribute__((address_space(1))) unsigned int*)g,
        (__attribute__((address_space(3))) unsigned int*)l, 16, 0, 0);
}

// ---------------------------------------------------------------------------
// 128x128 MFMA GEMM core. A: row-major [M,K] (lda). B: [N,K] row-major (ldb).
// Staging: global_load_lds width=16, linear LDS [128][64], st-16x32 swizzle:
//   LDS[r][cb] holds global 16B-block (cb ^ (r&7)); reads XOR the block index.
// 4 waves (2x2), each 64x64 via 4x4 frags of mfma_f32_16x16x32_bf16.
// ---------------------------------------------------------------------------
__device__ __forceinline__ void gemm_core(
    const bf16* __restrict__ A, int lda,
    const bf16* __restrict__ B, int ldb,
    int kBeg, int kEnd, int m0, int n0, f32x4 acc[4][4])
{
    __shared__ __align__(16) bf16 Als[BM][BK];
    __shared__ __align__(16) bf16 Bls[BN][BK];
    const int t    = threadIdx.x;
    const int lane = t & 63;
    const int wid  = t >> 6;
    const int wm   = (wid >> 1) * 64;
    const int wn   = (wid & 1) * 64;
    const int fr   = lane & 15;
    const int kq   = lane >> 4;                 // 0..3
    const int r_   = t >> 3;                    // staging row 0..31
    const int cbs  = (t & 7) ^ (r_ & 7);        // swizzled SOURCE 16B-block
    const int dcol = (t & 7) * 8;               // linear LDS dest col (elems)
    const int cs0  = ((kq)     ^ (fr & 7)) * 8; // swizzled read col, k-half 0
    const int cs1  = ((kq + 4) ^ (fr & 7)) * 8; // swizzled read col, k-half 1

    for (int k0 = kBeg; k0 < kEnd; k0 += BK) {
        const bf16* Ag = A + (size_t)(m0 + r_) * lda + (k0 + cbs * 8);
        const bf16* Bg = B + (size_t)(n0 + r_) * ldb + (k0 + cbs * 8);
        #pragma unroll
        for (int i = 0; i < 4; ++i)
            gload16(Ag + (size_t)(i * 32) * lda, &Als[i * 32 + r_][dcol]);
        #pragma unroll
        for (int i = 0; i < 4; ++i)
            gload16(Bg + (size_t)(i * 32) * ldb, &Bls[i * 32 + r_][dcol]);
        __syncthreads();
        #pragma unroll
        for (int h = 0; h < 2; ++h) {
            const int cs = h ? cs1 : cs0;
            bf16x8 af[4], bg[4];
            #pragma unroll
            for (int f = 0; f < 4; ++f) {
                af[f] = *(const bf16x8*)&Als[wm + f * 16 + fr][cs];
                bg[f] = *(const bf16x8*)&Bls[wn + f * 16 + fr][cs];
            }
            #pragma unroll
            for (int fm = 0; fm < 4; ++fm)
                #pragma unroll
                for (int fn = 0; fn < 4; ++fn)
                    acc[fm][fn] = __builtin_amdgcn_mfma_f32_16x16x32_bf16(
                        af[fm], bg[fn], acc[fm][fn], 0, 0, 0);
        }
        __syncthreads();
    }
}

// ---------------------------------------------------------------------------
// Prep kernels
// ---------------------------------------------------------------------------
__global__ __launch_bounds__(256) void convert_w_kernel(
    const float* __restrict__ qw, const float* __restrict__ kw,
    const float* __restrict__ vw, const float* __restrict__ pw,
    bf16* __restrict__ dst)
{
    const int which = blockIdx.y;
    const float* src = which == 0 ? qw : which == 1 ? kw : which == 2 ? vw : pw;
    bf16* d = dst + (size_t)which * (CC * CC);
    const int f4 = blockIdx.x * 256 + threadIdx.x;
    float4 v = ((const float4*)src)[f4];
    bf16x4 o;
    o[0] = (bf16)v.x; o[1] = (bf16)v.y; o[2] = (bf16)v.z; o[3] = (bf16)v.w;
    ((bf16x4*)d)[f4] = o;
}

__global__ __launch_bounds__(256) void gn_stats_kernel(
    const float* __restrict__ x, float* __restrict__ mr)
{
    const int bg = blockIdx.x;                        // b*32+g
    const float4* base = (const float4*)(x + (size_t)bg * 16 * NN);
    const int t = threadIdx.x;
    float s = 0.f, sq = 0.f;
    #pragma unroll 4
    for (int i = 0; i < 64; ++i) {
        float4 v = base[i * 256 + t];
        s  += v.x + v.y + v.z + v.w;
        sq += v.x * v.x + v.y * v.y + v.z * v.z + v.w * v.w;
    }
    #pragma unroll
    for (int o = 32; o > 0; o >>= 1) { s += __shfl_xor(s, o); sq += __shfl_xor(sq, o); }
    __shared__ float rs[4], rq[4];
    const int lane = t & 63, wid = t >> 6;
    if (lane == 0) { rs[wid] = s; rq[wid] = sq; }
    __syncthreads();
    if (t == 0) {
        float S = rs[0] + rs[1] + rs[2] + rs[3];
        float Q = rq[0] + rq[1] + rq[2] + rq[3];
        const float invn = 1.f / 65536.f;
        float mean = S * invn;
        float var  = Q * invn - mean * mean;
        mr[bg * 2]     = mean;
        mr[bg * 2 + 1] = rsqrtf(var + 1e-6f);
    }
}

// GN apply + transpose: x[b,c,n] fp32 -> hT[b,n,c] bf16 (4x4 reg blocklets)
__global__ __launch_bounds__(256) void gn_apply_T_kernel(
    const float* __restrict__ x, const float* __restrict__ gw,
    const float* __restrict__ gb, const float* __restrict__ mr,
    bf16* __restrict__ hT)
{
    const int b  = blockIdx.z;
    const int n0 = blockIdx.x * 64;
    const int c0 = blockIdx.y * 64;
    const int t  = threadIdx.x;
    const int tn = t & 15, tc = t >> 4;
    float o[4][4];
    #pragma unroll
    for (int j = 0; j < 4; ++j) {
        const int c = c0 + tc * 4 + j;
        const int bg = b * 32 + (c >> 4);
        const float mean = mr[bg * 2], rstd = mr[bg * 2 + 1];
        const float w  = gw[c] * rstd;
        const float bb = gb[c] - mean * w;
        float4 v = *(const float4*)(x + ((size_t)(b * CC + c)) * NN + n0 + tn * 4);
        o[j][0] = v.x * w + bb; o[j][1] = v.y * w + bb;
        o[j][2] = v.z * w + bb; o[j][3] = v.w * w + bb;
    }
    bf16* dst = hT + (size_t)b * (size_t)NN * CC;
    #pragma unroll
    for (int i = 0; i < 4; ++i) {
        bf16x4 w4;
        w4[0] = (bf16)o[0][i]; w4[1] = (bf16)o[1][i];
        w4[2] = (bf16)o[2][i]; w4[3] = (bf16)o[3][i];
        *(bf16x4*)(dst + (size_t)(n0 + tn * 4 + i) * CC + c0 + tc * 4) = w4;
    }
}

// ---------------------------------------------------------------------------
// GEMM kernels
// ---------------------------------------------------------------------------
// qT/kT[b][n][o] = sum_c hT[b][n][c] * w[o][c] (+bias) (*SCALE for q)
__global__ __launch_bounds__(256) void qk_gemm_kernel(
    const bf16* __restrict__ hT, const bf16* __restrict__ wbf,
    const float* __restrict__ qb, const float* __restrict__ kb,
    bf16* __restrict__ qT, bf16* __restrict__ kT)
{
    const int z = blockIdx.z, b = z >> 1, w = z & 1;
    const size_t CN = (size_t)CC * NN;
    const bf16* A = hT + (size_t)b * CN;
    const bf16* B = wbf + (size_t)w * CC * CC;
    const float* bias = w ? kb : qb;
    bf16* outp = (w ? kT : qT) + (size_t)b * CN;
    const int m0 = blockIdx.y * BM, n0 = blockIdx.x * BN;
    f32x4 acc[4][4] = {};
    gemm_core(A, CC, B, CC, 0, CC, m0, n0, acc);
    const int lane = threadIdx.x & 63, wid = threadIdx.x >> 6;
    const int wm = (wid >> 1) * 64, wn = (wid & 1) * 64;
    const int cf = lane & 15, rb = (lane >> 4) * 4;
    #pragma unroll
    for (int fm = 0; fm < 4; ++fm)
      #pragma unroll
      for (int fn = 0; fn < 4; ++fn)
        #pragma unroll
        for (int r = 0; r < 4; ++r) {
            int row = m0 + wm + fm * 16 + rb + r;
            int col = n0 + wn + fn * 16 + cf;
            float val = acc[fm][fn][r] + bias[col];
            if (w == 0) val *= SCALE;
            outp[(size_t)row * CC + col] = (bf16)val;
        }
}

// v[b][c][n] = sum_k vw[c][k] * hT[b][n][k] + vb[c]
__global__ __launch_bounds__(256) void v_gemm_kernel(
    const bf16* __restrict__ vw, const bf16* __restrict__ hT,
    const float* __restrict__ vb, bf16* __restrict__ vout)
{
    const int b = blockIdx.z;
    const size_t CN = (size_t)CC * NN;
    const bf16* B = hT + (size_t)b * CN;
    bf16* outp = vout + (size_t)b * CN;
    const int m0 = blockIdx.y * BM, n0 = blockIdx.x * BN;
    f32x4 acc[4][4] = {};
    gemm_core(vw, CC, B, CC, 0, CC, m0, n0, acc);
    const int lane = threadIdx.x & 63, wid = threadIdx.x >> 6;
    const int wm = (wid >> 1) * 64, wn = (wid & 1) * 64;
    const int cf = lane & 15, rb = (lane >> 4) * 4;
    #pragma unroll
    for (int fm = 0; fm < 4; ++fm)
      #pragma unroll
      for (int fn = 0; fn < 4; ++fn)
        #pragma unroll
        for (int r = 0; r < 4; ++r) {
            int row = m0 + wm + fm * 16 + rb + r;    // c
            int col = n0 + wn + fn * 16 + cf;        // n
            outp[(size_t)row * NN + col] = (bf16)(acc[fm][fn][r] + vb[row]);
        }
}

// E[i][j] = exp(qT_b[i,:].kT_b[j,:]); rowsum[i] += partial sums (atomic)
__global__ __launch_bounds__(256) void se_gemm_kernel(
    const bf16* __restrict__ qT_b, const bf16* __restrict__ kT_b,
    bf16* __restrict__ E, float* __restrict__ rowsum)
{
    const int m0 = blockIdx.y * BM, n0 = blockIdx.x * BN;
    f32x4 acc[4][4] = {};
    gemm_core(qT_b, CC, kT_b, CC, 0, CC, m0, n0, acc);
    const int lane = threadIdx.x & 63, wid = threadIdx.x >> 6;
    const int wm = (wid >> 1) * 64, wn = (wid & 1) * 64;
    const int cf = lane & 15, rb = (lane >> 4) * 4;
    #pragma unroll
    for (int fm = 0; fm < 4; ++fm)
      #pragma unroll
      for (int fn = 0; fn < 4; ++fn)
        #pragma unroll
        for (int r = 0; r < 4; ++r) {
            float e = __expf(fminf(acc[fm][fn][r], 60.f));
            acc[fm][fn][r] = e;
            E[(size_t)(m0 + wm + fm * 16 + rb + r) * NN
              + (n0 + wn + fn * 16 + cf)] = (bf16)e;
        }
    // per-row partial sums -> atomic
    #pragma unroll
    for (int fm = 0; fm < 4; ++fm)
      #pragma unroll
      for (int r = 0; r < 4; ++r) {
          float s = acc[fm][0][r] + acc[fm][1][r] + acc[fm][2][r] + acc[fm][3][r];
          s += __shfl_xor(s, 1); s += __shfl_xor(s, 2);
          s += __shfl_xor(s, 4); s += __shfl_xor(s, 8);
          if (cf == 0)
              atomicAdd(&rowsum[m0 + wm + fm * 16 + rb + r], s);
      }
}

// attnTf[i][c] += sum_{j in split} E[i][j] * v[c][j]   (split-K=4, atomics)
__global__ __launch_bounds__(256) void pv_gemm_kernel(
    const bf16* __restrict__ E, const bf16* __restrict__ v_b,
    float* __restrict__ attnTf)
{
    const int m0 = blockIdx.y * BM, n0 = blockIdx.x * BN;
    const int kB = blockIdx.z * (NN / 4);
    f32x4 acc[4][4] = {};
    gemm_core(E, NN, v_b, NN, kB, kB + NN / 4, m0, n0, acc);
    const int lane = threadIdx.x & 63, wid = threadIdx.x >> 6;
    const int wm = (wid >> 1) * 64, wn = (wid & 1) * 64;
    const int cf = lane & 15, rb = (lane >> 4) * 4;
    #pragma unroll
    for (int fm = 0; fm < 4; ++fm)
      #pragma unroll
      for (int fn = 0; fn < 4; ++fn)
        #pragma unroll
        for (int r = 0; r < 4; ++r)
            atomicAdd(&attnTf[(size_t)(m0 + wm + fm * 16 + rb + r) * CC
                              + (n0 + wn + fn * 16 + cf)], acc[fm][fn][r]);
}

// attnT_b[i][c] = attnTf[i][c] / rowsum[i]  (fp32 -> bf16)
__global__ __launch_bounds__(256) void norm_kernel(
    const float* __restrict__ attnTf, const float* __restrict__ rowsum,
    bf16* __restrict__ attnT_b)
{
    const int idx = blockIdx.x * 256 + threadIdx.x;   // float4 index
    const int i = idx >> 7;                           // 128 float4 per row
    const float inv = 1.f / rowsum[i];
    float4 u = ((const float4*)attnTf)[idx];
    bf16x4 o;
    o[0] = (bf16)(u.x * inv); o[1] = (bf16)(u.y * inv);
    o[2] = (bf16)(u.z * inv); o[3] = (bf16)(u.w * inv);
    ((bf16x4*)attnT_b)[idx] = o;
}

// out[b][o][n] = sum_c attnT[b][n][c] * pw[o][c] + pb[o] + x[b][o][n]
__global__ __launch_bounds__(256) void proj_gemm_kernel(
    const bf16* __restrict__ attnT, const bf16* __restrict__ pwb,
    const float* __restrict__ pb, const float* __restrict__ x,
    float* __restrict__ outp)
{
    const int b = blockIdx.z;
    const size_t CN = (size_t)CC * NN;
    const bf16* A = attnT + (size_t)b * CN;
    const int m0 = blockIdx.y * BM, n0 = blockIdx.x * BN;
    f32x4 acc[4][4] = {};
    gemm_core(A, CC, pwb, CC, 0, CC, m0, n0, acc);
    const int lane = threadIdx.x & 63, wid = threadIdx.x >> 6;
    const int wm = (wid >> 1) * 64, wn = (wid & 1) * 64;
    const int cf = lane & 15, rb = (lane >> 4) * 4;
    #pragma unroll
    for (int fm = 0; fm < 4; ++fm)
      #pragma unroll
      for (int fn = 0; fn < 4; ++fn) {
          int rowg = m0 + wm + fm * 16 + rb;          // n (contiguous in mem)
          int colg = n0 + wn + fn * 16 + cf;          // o
          size_t base = (size_t)b * CN + (size_t)colg * NN + rowg;
          float4 rx = *(const float4*)(x + base);
          float pbv = pb[colg];
          float4 o;
          o.x = acc[fm][fn][0] + pbv + rx.x;
          o.y = acc[fm][fn][1] + pbv + rx.y;
          o.z = acc[fm][fn][2] + pbv + rx.z;
          o.w = acc[fm][fn][3] + pbv + rx.w;
          *(float4*)(outp + base) = o;
      }
}

// ---------------------------------------------------------------------------
extern "C" void kernel_launch(void* const* d_in, const int* in_sizes, int n_in,
                              void* d_out, int out_size, void* d_ws, size_t ws_size,
                              hipStream_t stream)
{
    const float* x   = (const float*)d_in[0];
    const float* gnw = (const float*)d_in[1];
    const float* gnb = (const float*)d_in[2];
    const float* qw  = (const float*)d_in[3];
    const float* qb  = (const float*)d_in[4];
    const float* kw  = (const float*)d_in[5];
    const float* kb  = (const float*)d_in[6];
    const float* vw  = (const float*)d_in[7];
    const float* vb  = (const float*)d_in[8];
    const float* pw  = (const float*)d_in[9];
    const float* pb  = (const float*)d_in[10];
    float* outp = (float*)d_out;

    char* ws = (char*)d_ws;
    size_t off = 0;
    auto alloc = [&](size_t bytes) -> char* {
        char* p = ws + off;
        off = (off + bytes + 255) & ~(size_t)255;
        return p;
    };
    const size_t CN = (size_t)CC * NN;
    bf16*  wbf    = (bf16*)alloc(4 * (size_t)CC * CC * sizeof(bf16)); // 2MB
    bf16*  hT     = (bf16*)alloc(2 * CN * sizeof(bf16));              // 8MB
    bf16*  qT     = (bf16*)alloc(2 * CN * sizeof(bf16));              // 8MB
    bf16*  kT     = (bf16*)alloc(2 * CN * sizeof(bf16));              // 8MB
    bf16*  vbuf   = (bf16*)alloc(2 * CN * sizeof(bf16));              // 8MB
    bf16*  attnT  = (bf16*)alloc(2 * CN * sizeof(bf16));              // 8MB
    bf16*  E      = (bf16*)alloc((size_t)NN * NN * sizeof(bf16));     // 32MB
    float* attnTf = (float*)alloc(CN * sizeof(float) + NN * sizeof(float)); // 8MB+16KB
    float* rowsum = attnTf + CN;
    float* mr     = (float*)alloc(64 * 2 * sizeof(float));

    convert_w_kernel<<<dim3(256, 4), 256, 0, stream>>>(qw, kw, vw, pw, wbf);
    gn_stats_kernel<<<64, 256, 0, stream>>>(x, mr);
    gn_apply_T_kernel<<<dim3(NN / 64, CC / 64, 2), 256, 0, stream>>>(
        x, gnw, gnb, mr, hT);

    qk_gemm_kernel<<<dim3(CC / BN, NN / BM, 4), 256, 0, stream>>>(
        hT, wbf, qb, kb, qT, kT);
    v_gemm_kernel<<<dim3(NN / BN, CC / BM, 2), 256, 0, stream>>>(
        wbf + 2 * (size_t)CC * CC, hT, vb, vbuf);

    for (int b = 0; b < 2; ++b) {
        hipMemsetAsync(attnTf, 0, CN * sizeof(float) + NN * sizeof(float), stream);
        se_gemm_kernel<<<dim3(NN / BN, NN / BM), 256, 0, stream>>>(
            qT + (size_t)b * CN, kT + (size_t)b * CN, E, rowsum);
        pv_gemm_kernel<<<dim3(CC / BN, NN / BM, 4), 256, 0, stream>>>(
            E, vbuf + (size_t)b * CN, attnTf);
        norm_kernel<<<CN / 1024, 256, 0, stream>>>(
            attnTf, rowsum, attnT + (size_t)b * CN);
    }

    proj_gemm_kernel<<<dim3(CC / BN, NN / BM, 2), 256, 0, stream>>>(
        attnT, wbf + 3 * (size_t)CC * CC, pb, x, outp);
}